// Round 8
// baseline (199.415 us; speedup 1.0000x reference)
//
#include <hip/hip_runtime.h>
#include <hip/hip_cooperative_groups.h>
#include <stdint.h>

namespace cg = cooperative_groups;

#define BB 8
#define CC 19
#define HH 512
#define WW 1024
#define KK 15
#define RR 7
#define TH 8
#define NROWS (TH + 2*RR)          // 22 staged rows
#define ROW_DW 260                 // 2 pad dw + 256 data dw + 2 pad dw
#define NPIX (BB*HH*WW)            // 4194304
#define NBLK (BB*(HH/TH))          // 512
#define SENT4 0x1F1F1F1Fu          // sentinel class 31: xor with 0..18 stays in [1,31]

static __device__ __forceinline__ uint32_t alignb(uint32_t hi, uint32_t lo, unsigned s) {
#if __has_builtin(__builtin_amdgcn_alignbyte)
  return __builtin_amdgcn_alignbyte(hi, lo, s);
#else
  return (uint32_t)(((((uint64_t)hi) << 32) | lo) >> (8u * s));
#endif
}

__global__ __launch_bounds__(256) void wce_main(const float* __restrict__ in,
                                                const int* __restrict__ tg,
                                                float* __restrict__ part,
                                                float* __restrict__ out) {
  __shared__ uint32_t T[NROWS][ROW_DW];
  __shared__ float wpart[4];
  const int tid = threadIdx.x;
  const int blk = blockIdx.x;
  const int bb  = blk >> 6;           // 64 h-blocks per batch (512/TH)
  const int h0  = (blk & 63) * TH;

  // ---- stage 22 target rows as packed bytes with sentinel padding ----
  const int total = NROWS * ROW_DW;
  for (int idx = tid; idx < total; idx += 256) {
    const int r = idx / ROW_DW;
    const int d = idx - r * ROW_DW;
    uint32_t v = SENT4;
    const int h = h0 - RR + r;
    if (h >= 0 && h < HH && d >= 2 && d < 258) {
      const int4 t4 = *reinterpret_cast<const int4*>(&tg[(bb*HH + h)*WW + (d - 2)*4]);
      v = (uint32_t)(t4.x & 0xff)        | ((uint32_t)(t4.y & 0xff) << 8)
        | ((uint32_t)(t4.z & 0xff) << 16) | ((uint32_t)(t4.w & 0xff) << 24);
    }
    (&T[0][0])[idx] = v;
  }
  __syncthreads();

  const int g = tid;                  // this thread's 4-px group: w = 4g..4g+3
  float acc = 0.0f;

  #pragma unroll 1
  for (int s = 0; s < TH; ++s) {
    const int hh = h0 + s;
    const uint32_t c4 = T[s + RR][g + 2];   // center classes, packed bytes

    // issue the 4 input gathers early; they drain under the window compute
    const int c0 = (int)(c4 & 0xff), c1 = (int)((c4 >> 8) & 0xff);
    const int c2 = (int)((c4 >> 16) & 0xff), c3 = (int)((c4 >> 24) & 0xff);
    const int base = bb*CC*HH*WW + hh*WW + 4*g;
    const float x0 = in[base + c0*(HH*WW) + 0];
    const float x1 = in[base + c1*(HH*WW) + 1];
    const float x2 = in[base + c2*(HH*WW) + 2];
    const float x3 = in[base + c3*(HH*WW) + 3];

    // ---- SWAR non-match count over the 15x15 window ----
    uint32_t nm = 0;
    #pragma unroll
    for (int wr = 0; wr < KK; ++wr) {
      const uint32_t* row = &T[s + wr][g];  // dwords g..g+4 cover w = 4g-8 .. 4g+11
      const uint32_t d0 = row[0], d1 = row[1], d2 = row[2], d3 = row[3], d4 = row[4];
      #define CMPW(rhs) do { uint32_t t_ = ((rhs) ^ c4) + 0x7f7f7f7fu; \
                             nm += (t_ & 0x80808080u) >> 7; } while (0)
      CMPW(alignb(d1, d0, 1));   // dw = -7
      CMPW(alignb(d1, d0, 2));   // dw = -6
      CMPW(alignb(d1, d0, 3));   // dw = -5
      CMPW(d1);                  // dw = -4
      CMPW(alignb(d2, d1, 1));   // dw = -3
      CMPW(alignb(d2, d1, 2));   // dw = -2
      CMPW(alignb(d2, d1, 3));   // dw = -1
      CMPW(d2);                  // dw =  0
      CMPW(alignb(d3, d2, 1));   // dw = +1
      CMPW(alignb(d3, d2, 2));   // dw = +2
      CMPW(alignb(d3, d2, 3));   // dw = +3
      CMPW(d3);                  // dw = +4
      CMPW(alignb(d4, d3, 1));   // dw = +5
      CMPW(alignb(d4, d3, 2));   // dw = +6
      CMPW(alignb(d4, d3, 3));   // dw = +7
      #undef CMPW
    }
    const int n0 = 225 - (int)( nm        & 0xff);
    const int n1 = 225 - (int)((nm >> 8)  & 0xff);
    const int n2 = 225 - (int)((nm >> 16) & 0xff);
    const int n3 = 225 - (int)((nm >> 24) & 0xff);
    acc += x0 * (225.0f / (float)n0);
    acc += x1 * (225.0f / (float)n1);
    acc += x2 * (225.0f / (float)n2);
    acc += x3 * (225.0f / (float)n3);
  }

  // ---- block reduction ----
  #pragma unroll
  for (int off = 32; off > 0; off >>= 1) acc += __shfl_down(acc, off, 64);
  const int lane = tid & 63, wv = tid >> 6;
  if (lane == 0) wpart[wv] = acc;
  __syncthreads();
  if (tid == 0) part[blk] = wpart[0] + wpart[1] + wpart[2] + wpart[3];

  // ---- grid-wide barrier (cooperative launch), then block 0 reduces ----
  __threadfence();                    // publish partials at device scope
  cg::this_grid().sync();             // proper cross-XCD grid barrier

  if (blk == 0) {
    float a = 0.0f;
    for (int i = tid; i < NBLK; i += 256) a += part[i];   // fixed order: deterministic
    #pragma unroll
    for (int off = 32; off > 0; off >>= 1) a += __shfl_down(a, off, 64);
    if (lane == 0) wpart[wv] = a;
    __syncthreads();
    if (tid == 0) {
      const float tot = wpart[0] + wpart[1] + wpart[2] + wpart[3];
      out[0] = -tot / (float)NPIX;
    }
  }
}

extern "C" void kernel_launch(void* const* d_in, const int* in_sizes, int n_in,
                              void* d_out, int out_size, void* d_ws, size_t ws_size,
                              hipStream_t stream) {
  const float* in = (const float*)d_in[0];
  const int*   tg = (const int*)d_in[1];
  float* out  = (float*)d_out;
  float* part = (float*)d_ws;

  void* args[] = { (void*)&in, (void*)&tg, (void*)&part, (void*)&out };
  hipLaunchCooperativeKernel((const void*)wce_main, dim3(NBLK), dim3(256),
                             args, 0, stream);
}

// Round 9
// 53.867 us; speedup vs baseline: 3.7020x; 3.7020x over previous
//
#include <hip/hip_runtime.h>
#include <stdint.h>

#define BB 8
#define CC 19
#define HH 512
#define WW 1024
#define KK 15
#define RR 7
#define TH 8
#define NROWS (TH + 2*RR)          // 22 staged rows
#define P_DW 34                    // 1 pad dw + 32 data dw + 1 pad dw (1024 bits + pads)
#define NPIX (BB*HH*WW)            // 4194304
#define NBLK (BB*(HH/TH))          // 512

__global__ __launch_bounds__(256) void wce_main(const float* __restrict__ in,
                                                const int* __restrict__ tg,
                                                float* __restrict__ part) {
  // per-class bit-planes of the staged 22-row strip: bit = (class at that pixel)
  __shared__ uint32_t P[CC][NROWS][P_DW];     // 19*22*34*4 = 56848 B
  __shared__ uint32_t Cc[TH][256];            // packed center classes, 8192 B
  __shared__ float wpart[4];
  const int tid = threadIdx.x;
  const int blk = blockIdx.x;
  const int bb  = blk >> 6;           // 64 h-blocks per batch (512/TH)
  const int h0  = (blk & 63) * TH;

  // ---- zero the bit-planes ----
  uint32_t* pflat = &P[0][0][0];
  #pragma unroll 4
  for (int i = tid; i < CC*NROWS*P_DW; i += 256) pflat[i] = 0;
  __syncthreads();

  // ---- build bit-planes (zero-padded borders = reference's zero box-filter pad) ----
  for (int idx = tid; idx < NROWS*256; idx += 256) {
    const int r = idx >> 8, d = idx & 255;
    const int h = h0 - RR + r;
    if (h >= 0 && h < HH) {
      const int4 t4 = *reinterpret_cast<const int4*>(&tg[(bb*HH + h)*WW + d*4]);
      const int rc = r - RR;
      if (rc >= 0 && rc < TH)
        Cc[rc][d] = (uint32_t)(t4.x & 0xff)        | ((uint32_t)(t4.y & 0xff) << 8)
                  | ((uint32_t)(t4.z & 0xff) << 16) | ((uint32_t)(t4.w & 0xff) << 24);
      const int col = d * 4;              // cols col..col+3 live in the same dword
      const int dw  = 1 + (col >> 5);
      const int b   = col & 31;
      atomicOr(&P[t4.x][r][dw], 1u << (b + 0));
      atomicOr(&P[t4.y][r][dw], 1u << (b + 1));
      atomicOr(&P[t4.z][r][dw], 1u << (b + 2));
      atomicOr(&P[t4.w][r][dw], 1u << (b + 3));
    }
  }
  __syncthreads();

  const int g = tid;                  // this thread's 4-px group: w = 4g..4g+3
  float acc = 0.0f;

  #pragma unroll 1
  for (int s = 0; s < TH; ++s) {
    const uint32_t c4 = Cc[s][g];     // center classes, packed bytes

    // issue the 4 input gathers early; they drain under the popcount loop
    const int c0 = (int)(c4 & 0xff), c1 = (int)((c4 >> 8) & 0xff);
    const int c2 = (int)((c4 >> 16) & 0xff), c3 = (int)((c4 >> 24) & 0xff);
    const int base = bb*CC*HH*WW + (h0 + s)*WW + 4*g;
    const float x0 = in[base + c0*(HH*WW) + 0];
    const float x1 = in[base + c1*(HH*WW) + 1];
    const float x2 = in[base + c2*(HH*WW) + 2];
    const float x3 = in[base + c3*(HH*WW) + 3];

    // ---- bit-plane popcount over the 15x15 window (rows s..s+14) ----
    int cnt[4];
    #pragma unroll
    for (int i = 0; i < 4; ++i) {
      const int c  = (int)((c4 >> (8*i)) & 0xff);
      const int lb = 4*g + i - 7;           // lowest window column
      const int q  = (lb >> 5) + 1;         // arithmetic shift: floor, pad-aware
      const int sh = lb & 31;
      const uint32_t* pr = &P[c][s][q];
      int cn = 0;
      #pragma unroll
      for (int wr = 0; wr < KK; ++wr) {
        const uint32_t lo = pr[0], hi = pr[1];   // ds_read2_b32
        cn += __popc(__builtin_amdgcn_alignbit(hi, lo, sh) & 0x7fffu);
        pr += P_DW;
      }
      cnt[i] = cn;                          // >= 1 (center bit always set)
    }
    acc += x0 * (225.0f / (float)cnt[0]);
    acc += x1 * (225.0f / (float)cnt[1]);
    acc += x2 * (225.0f / (float)cnt[2]);
    acc += x3 * (225.0f / (float)cnt[3]);
  }

  // ---- block reduction ----
  #pragma unroll
  for (int off = 32; off > 0; off >>= 1) acc += __shfl_down(acc, off, 64);
  const int lane = tid & 63, wv = tid >> 6;
  if (lane == 0) wpart[wv] = acc;
  __syncthreads();
  if (tid == 0) part[blk] = wpart[0] + wpart[1] + wpart[2] + wpart[3];
}

__global__ __launch_bounds__(256) void wce_reduce(const float* __restrict__ part,
                                                  float* __restrict__ out, int n) {
  __shared__ float wpart[4];
  float a = 0.0f;
  for (int i = threadIdx.x; i < n; i += 256) a += part[i];
  #pragma unroll
  for (int off = 32; off > 0; off >>= 1) a += __shfl_down(a, off, 64);
  const int lane = threadIdx.x & 63, wv = threadIdx.x >> 6;
  if (lane == 0) wpart[wv] = a;
  __syncthreads();
  if (threadIdx.x == 0) {
    const float tot = wpart[0] + wpart[1] + wpart[2] + wpart[3];
    out[0] = -tot / (float)NPIX;
  }
}

extern "C" void kernel_launch(void* const* d_in, const int* in_sizes, int n_in,
                              void* d_out, int out_size, void* d_ws, size_t ws_size,
                              hipStream_t stream) {
  const float* in = (const float*)d_in[0];
  const int*   tg = (const int*)d_in[1];
  float* out  = (float*)d_out;
  float* part = (float*)d_ws;

  wce_main<<<NBLK, 256, 0, stream>>>(in, tg, part);
  wce_reduce<<<1, 256, 0, stream>>>(part, out, NBLK);
}